// Round 5
// baseline (393.615 us; speedup 1.0000x reference)
//
#include <hip/hip_runtime.h>

typedef unsigned short u16;
typedef __attribute__((ext_vector_type(8))) short bf16x8;
typedef __attribute__((ext_vector_type(4))) float f32x4;
typedef __attribute__((ext_vector_type(8))) unsigned short u16x8;
typedef __attribute__((ext_vector_type(4))) unsigned short u16x4;
typedef __attribute__((ext_vector_type(4))) float f32x4v;

#define LOG2E 1.4426950408889634f

// B=2, S=2048, D=1024, H=16, HD=64
#define SB 2048
#define DB 1024
#define NH 16
#define HD 64

__device__ __forceinline__ u16 f2bf(float f) {
  unsigned u = __float_as_uint(f);
  return (u16)((u + 0x7FFFu + ((u >> 16) & 1u)) >> 16);
}
__device__ __forceinline__ float bf2f(u16 h) {
  return __uint_as_float(((unsigned)h) << 16);
}

__device__ __forceinline__ void gload_lds16(const void* g, void* l) {
  __builtin_amdgcn_global_load_lds((const __attribute__((address_space(1))) void*)g,
                                   (__attribute__((address_space(3))) void*)l, 16, 0, 0);
}

// ---- conversion kernels ----

__global__ void conv_x_kernel(const float* __restrict__ in, u16* __restrict__ out) {
  int i = blockIdx.x * blockDim.x + threadIdx.x;  // each handles 8 elems
  const f32x4v* p = (const f32x4v*)in + (size_t)i * 2;
  f32x4v a = p[0], b = p[1];
  u16x8 o;
  o[0] = f2bf(a[0]); o[1] = f2bf(a[1]); o[2] = f2bf(a[2]); o[3] = f2bf(a[3]);
  o[4] = f2bf(b[0]); o[5] = f2bf(b[1]); o[6] = f2bf(b[2]); o[7] = f2bf(b[3]);
  *((u16x8*)out + i) = o;
}

__global__ void conv_bias_kernel(const float* __restrict__ in, const float* __restrict__ coef,
                                 u16* __restrict__ out) {
  int i = blockIdx.x * blockDim.x + threadIdx.x;
  float c = coef[0];
  const f32x4v* p = (const f32x4v*)in + (size_t)i * 2;
  f32x4v a = p[0], b = p[1];
  u16x8 o;
  o[0] = f2bf(a[0] * c); o[1] = f2bf(a[1] * c); o[2] = f2bf(a[2] * c); o[3] = f2bf(a[3] * c);
  o[4] = f2bf(b[0] * c); o[5] = f2bf(b[1] * c); o[6] = f2bf(b[2] * c); o[7] = f2bf(b[3] * c);
  *((u16x8*)out + i) = o;
}

// transpose W [K][N] -> Wt [N][K] in bf16, z selects Wq/Wk/Wv
__global__ void conv_wt_kernel(const float* __restrict__ Wq, const float* __restrict__ Wk,
                               const float* __restrict__ Wv, u16* __restrict__ Wt) {
  __shared__ float tile[32][33];
  int z = blockIdx.z;
  const float* W = (z == 0) ? Wq : (z == 1) ? Wk : Wv;
  int k0 = blockIdx.x * 32, n0 = blockIdx.y * 32;
  int tx = threadIdx.x;
  for (int i = threadIdx.y; i < 32; i += 8)
    tile[i][tx] = W[(size_t)(k0 + i) * DB + n0 + tx];
  __syncthreads();
  for (int i = threadIdx.y; i < 32; i += 8)
    Wt[(size_t)z * DB * DB + (size_t)(n0 + i) * DB + k0 + tx] = f2bf(tile[tx][i]);
}

// ---- QKV projection GEMM: [4096x1024] x [1024x1024] per z ----
// Q,K layout: [bh][s][64] bf16 ; V layout transposed: [bh][64][s]
__global__ __launch_bounds__(256) void gemm_qkv_kernel(
    const u16* __restrict__ X, const u16* __restrict__ Wt,
    const float* __restrict__ bq, const float* __restrict__ bk, const float* __restrict__ bv,
    u16* __restrict__ Q, u16* __restrict__ K, u16* __restrict__ V) {
  __shared__ __align__(16) u16 As[128 * 32];
  __shared__ __align__(16) u16 Bs[128 * 32];
  int z = blockIdx.z;
  const u16* Wz = Wt + (size_t)z * DB * DB;
  const float* bias = (z == 0) ? bq : (z == 1) ? bk : bv;
  int m0 = blockIdx.x * 128, n0 = blockIdx.y * 128;
  int tid = threadIdx.x, wid = tid >> 6, lane = tid & 63;
  int wr = wid >> 1, wc = wid & 1;
  int lrow = lane & 15, lk = lane >> 4;
  int srow = lane >> 2, scol = (lane & 3) * 8;

  f32x4 acc[4][4];
#pragma unroll
  for (int i = 0; i < 4; i++)
#pragma unroll
    for (int j = 0; j < 4; j++) acc[i][j] = (f32x4){0.f, 0.f, 0.f, 0.f};

  for (int k0 = 0; k0 < DB; k0 += 32) {
#pragma unroll
    for (int p = 0; p < 2; p++) {
      int c = p * 4 + wid;
      gload_lds16(X + (size_t)(m0 + c * 16 + srow) * DB + k0 + scol, &As[c * 512]);
      gload_lds16(Wz + (size_t)(n0 + c * 16 + srow) * DB + k0 + scol, &Bs[c * 512]);
    }
    __syncthreads();
    bf16x8 af[4], bf_[4];
#pragma unroll
    for (int i = 0; i < 4; i++)
      af[i] = *(const bf16x8*)&As[(wr * 64 + i * 16 + lrow) * 32 + lk * 8];
#pragma unroll
    for (int j = 0; j < 4; j++)
      bf_[j] = *(const bf16x8*)&Bs[(wc * 64 + j * 16 + lrow) * 32 + lk * 8];
#pragma unroll
    for (int i = 0; i < 4; i++)
#pragma unroll
      for (int j = 0; j < 4; j++)
        acc[i][j] = __builtin_amdgcn_mfma_f32_16x16x32_bf16(af[i], bf_[j], acc[i][j], 0, 0, 0);
    __syncthreads();
  }

  // epilogue: C row = (lane>>4)*4 + r, col = lane&15 per 16x16 block
#pragma unroll
  for (int j = 0; j < 4; j++) {
    int n = n0 + wc * 64 + j * 16 + lrow;
    float bb = bias[n];
    int h = n >> 6, hd = n & 63;
#pragma unroll
    for (int i = 0; i < 4; i++) {
      int mbase = m0 + wr * 64 + i * 16 + lk * 4;
      int b = mbase >> 11;
      int s = mbase & (SB - 1);
      int bh = b * NH + h;
      if (z == 2) {
        u16x4 pk;
#pragma unroll
        for (int r = 0; r < 4; r++) pk[r] = f2bf(acc[i][j][r] + bb);
        *(u16x4*)&V[((size_t)bh * HD + hd) * SB + s] = pk;
      } else {
        u16* dst = (z == 0) ? Q : K;
#pragma unroll
        for (int r = 0; r < 4; r++)
          dst[((size_t)bh * SB + (s + r)) * HD + hd] = f2bf(acc[i][j][r] + bb);
      }
    }
  }
}

// ---- flash attention ----
// grid (S/64, B*H); 4 waves x 16 q-rows; KV tile 64
__global__ __launch_bounds__(256) void attn_kernel(
    const u16* __restrict__ Q, const u16* __restrict__ K, const u16* __restrict__ Vt,
    const u16* __restrict__ biasS, const float* __restrict__ mask, float* __restrict__ out) {
  __shared__ __align__(16) u16 P[4][16 * 64];
  int bh = blockIdx.y;
  int b = bh >> 4, h = bh & 15;
  int q0 = blockIdx.x * 64;
  int tid = threadIdx.x, wid = tid >> 6, lane = tid & 63;
  int lrow = lane & 15, lk = lane >> 4;
  const u16* Qb = Q + (size_t)bh * SB * HD;
  const u16* Kb = K + (size_t)bh * SB * HD;
  const u16* Vb = Vt + (size_t)bh * HD * SB;
  const float* maskb = mask + b * SB;

  int qr = q0 + wid * 16 + lrow;  // A-frag row
  bf16x8 qa0 = *(const bf16x8*)&Qb[(size_t)qr * HD + lk * 8];
  bf16x8 qa1 = *(const bf16x8*)&Qb[(size_t)qr * HD + 32 + lk * 8];
  int qgr = q0 + wid * 16 + lk * 4;  // C-layout row base (+r)

  float mst[4], lst[4];
  f32x4 acc[4];
#pragma unroll
  for (int r = 0; r < 4; r++) { mst[r] = -3.0e38f; lst[r] = 0.f; }
#pragma unroll
  for (int d = 0; d < 4; d++) acc[d] = (f32x4){0.f, 0.f, 0.f, 0.f};
  u16* Pw = &P[wid][0];

  for (int kt = 0; kt < SB; kt += 64) {
    f32x4 s[4];
#pragma unroll
    for (int kb = 0; kb < 4; kb++) {
      int krow = kt + kb * 16 + lrow;  // B-frag col = k-row of K
      bf16x8 k0 = *(const bf16x8*)&Kb[(size_t)krow * HD + lk * 8];
      bf16x8 k1 = *(const bf16x8*)&Kb[(size_t)krow * HD + 32 + lk * 8];
      f32x4 t = __builtin_amdgcn_mfma_f32_16x16x32_bf16(qa0, k0, (f32x4){0.f, 0.f, 0.f, 0.f}, 0, 0, 0);
      s[kb] = __builtin_amdgcn_mfma_f32_16x16x32_bf16(qa1, k1, t, 0, 0, 0);
    }
    // scale + bias + mask (scores C layout: row qgr+r, col kt+kb*16+lrow)
#pragma unroll
    for (int kb = 0; kb < 4; kb++) {
      int kg = kt + kb * 16 + lrow;
      float mk = maskb[kg];
#pragma unroll
      for (int r = 0; r < 4; r++)
        s[kb][r] = s[kb][r] * 0.125f + bf2f(biasS[(size_t)(qgr + r) * SB + kg]) + mk;
    }
    // online softmax, per-row state on owner lanes
#pragma unroll
    for (int r = 0; r < 4; r++) {
      float t = fmaxf(fmaxf(s[0][r], s[1][r]), fmaxf(s[2][r], s[3][r]));
      t = fmaxf(t, __shfl_xor(t, 1));
      t = fmaxf(t, __shfl_xor(t, 2));
      t = fmaxf(t, __shfl_xor(t, 4));
      t = fmaxf(t, __shfl_xor(t, 8));
      float mn = fmaxf(mst[r], t);
      float al = exp2f((mst[r] - mn) * LOG2E);
      mst[r] = mn;
      float rs = 0.f;
#pragma unroll
      for (int kb = 0; kb < 4; kb++) {
        float p = exp2f((s[kb][r] - mn) * LOG2E);
        s[kb][r] = p;
        rs += p;
      }
      rs += __shfl_xor(rs, 1);
      rs += __shfl_xor(rs, 2);
      rs += __shfl_xor(rs, 4);
      rs += __shfl_xor(rs, 8);
      lst[r] = lst[r] * al + rs;
#pragma unroll
      for (int d = 0; d < 4; d++) acc[d][r] *= al;
    }
    // P (C layout) -> LDS, XOR-swizzled rows to kill 128B-row bank conflicts
#pragma unroll
    for (int kb = 0; kb < 4; kb++) {
#pragma unroll
      for (int r = 0; r < 4; r++) {
        int row = lk * 4 + r;
        int byte = row * 128 + (kb * 16 + lrow) * 2;
        byte ^= ((row & 7) << 4);
        *(u16*)((char*)Pw + byte) = f2bf(s[kb][r]);
      }
    }
    __syncthreads();
    // PV: A from P_lds (row=lane&15, k contiguous), B from Vt (col=d, k contiguous)
#pragma unroll
    for (int d = 0; d < 4; d++) {
#pragma unroll
      for (int ks = 0; ks < 2; ks++) {
        int byte = lrow * 128 + (ks * 32 + lk * 8) * 2;
        byte ^= ((lrow & 7) << 4);
        bf16x8 pa = *(const bf16x8*)((char*)Pw + byte);
        bf16x8 vb = *(const bf16x8*)&Vb[(size_t)(d * 16 + lrow) * SB + kt + ks * 32 + lk * 8];
        acc[d] = __builtin_amdgcn_mfma_f32_16x16x32_bf16(pa, vb, acc[d], 0, 0, 0);
      }
    }
    __syncthreads();
  }
  // epilogue: out[b][q][h*64 + d*16 + col] = acc/l
#pragma unroll
  for (int d = 0; d < 4; d++) {
#pragma unroll
    for (int r = 0; r < 4; r++) {
      int qg = qgr + r;
      out[((size_t)b * SB + qg) * DB + h * HD + d * 16 + lrow] = acc[d][r] / lst[r];
    }
  }
}

extern "C" void kernel_launch(void* const* d_in, const int* in_sizes, int n_in,
                              void* d_out, int out_size, void* d_ws, size_t ws_size,
                              hipStream_t stream) {
  const float* hs    = (const float*)d_in[0];
  const float* mask  = (const float*)d_in[1];
  const float* biasM = (const float*)d_in[2];
  const float* coef  = (const float*)d_in[3];
  const float* Wq    = (const float*)d_in[4];
  const float* bq    = (const float*)d_in[5];
  const float* Wk    = (const float*)d_in[6];
  const float* bk    = (const float*)d_in[7];
  const float* Wv    = (const float*)d_in[8];
  const float* bv    = (const float*)d_in[9];
  float* out = (float*)d_out;

  char* w = (char*)d_ws;
  u16* X     = (u16*)(w);                       // 4096x1024 bf16  (8 MB)
  u16* Wt    = (u16*)(w + 8u * 1024 * 1024);    // 3x1024x1024     (6 MB)
  u16* Qb    = (u16*)(w + 14u * 1024 * 1024);   // [32][2048][64]  (8 MB)
  u16* Kb    = (u16*)(w + 22u * 1024 * 1024);   // [32][2048][64]  (8 MB)
  u16* Vb    = (u16*)(w + 30u * 1024 * 1024);   // [32][64][2048]  (8 MB)
  u16* biasS = (u16*)(w + 38u * 1024 * 1024);   // [2048][2048]    (8 MB)

  conv_x_kernel<<<2048, 256, 0, stream>>>(hs, X);
  conv_wt_kernel<<<dim3(32, 32, 3), dim3(32, 8), 0, stream>>>(Wq, Wk, Wv, Wt);
  conv_bias_kernel<<<2048, 256, 0, stream>>>(biasM, coef, biasS);
  gemm_qkv_kernel<<<dim3(32, 8, 3), 256, 0, stream>>>(X, Wt, bq, bk, bv, Qb, Kb, Vb);
  attn_kernel<<<dim3(32, 32), 256, 0, stream>>>(Qb, Kb, Vb, biasS, mask, out);
}